// Round 2
// baseline (351.408 us; speedup 1.0000x reference)
//
#include <hip/hip_runtime.h>
#include <stdint.h>

#define MB (1ull << 20)

typedef __attribute__((ext_vector_type(8))) short bf16x8;
typedef __attribute__((ext_vector_type(8))) unsigned short u16x8;
typedef __attribute__((ext_vector_type(4))) float f32x4;

static __device__ __forceinline__ unsigned short f2bf(float f) {
    unsigned u = __builtin_bit_cast(unsigned, f);
    u += 0x7fffu + ((u >> 16) & 1u);   // round-to-nearest-even
    return (unsigned short)(u >> 16);
}
static __device__ __forceinline__ float bf2f(unsigned u16) {
    return __builtin_bit_cast(float, u16 << 16);
}

#define GLDS(gp, lp) __builtin_amdgcn_global_load_lds(                                   \
        (const __attribute__((address_space(1))) void*)(gp),                             \
        (__attribute__((address_space(3))) void*)(lp), 16, 0, 0)

// ---------------- prep: x f32 -> bf16 ----------------
__global__ __launch_bounds__(256) void cvt_x_kernel(const float* __restrict__ x,
                                                    unsigned short* __restrict__ xb, int n8) {
    int i = blockIdx.x * blockDim.x + threadIdx.x;
    if (i >= n8) return;
    const float4* px = (const float4*)x + (size_t)i * 2;
    float4 a = px[0], b = px[1];
    u16x8 o;
    o[0] = f2bf(a.x); o[1] = f2bf(a.y); o[2] = f2bf(a.z); o[3] = f2bf(a.w);
    o[4] = f2bf(b.x); o[5] = f2bf(b.y); o[6] = f2bf(b.z); o[7] = f2bf(b.w);
    ((u16x8*)xb)[i] = o;
}

// ---------------- prep: Wt[n][k] = concat(ek,wk)^T as bf16 ----------------
__global__ __launch_bounds__(256) void cvt_w_kernel(const float* __restrict__ ek,
                                                    const float* __restrict__ wk,
                                                    unsigned short* __restrict__ wt) {
    int t = blockIdx.x * blockDim.x + threadIdx.x;  // 0 .. 2048*128-1
    int n = t >> 7;
    int kb = (t & 127) * 8;
    const float* src = (n < 1024) ? ek : wk;
    int col = n & 1023;
    u16x8 o;
#pragma unroll
    for (int j = 0; j < 8; ++j) o[j] = f2bf(src[(size_t)(kb + j) * 1024 + col]);
    ((u16x8*)wt)[t] = o;
}

// ---------------- fused dual-gate GEMM: [16384,1024] x [1024,2048] ----------------
// 256x256 tile, BK=32, 8 waves (2M x 4N), 4-deep LDS pipeline, counted vmcnt(12).
// Epilogue stores bf16: a = 1-sigmoid(z) (n<1024) or w*x = sigmoid(z)*x (n>=1024).
__global__ __launch_bounds__(512, 2) void gate_gemm(const unsigned short* __restrict__ Xb,
                                                    const unsigned short* __restrict__ Wt,
                                                    const float* __restrict__ eb,
                                                    const float* __restrict__ wb,
                                                    const float* __restrict__ xf,
                                                    unsigned short* __restrict__ Ag,
                                                    unsigned short* __restrict__ WXg) {
    __shared__ alignas(16) unsigned short As[4][256 * 32];  // 64 KB
    __shared__ alignas(16) unsigned short Bs[4][256 * 32];  // 64 KB
    const int tid = threadIdx.x;
    const int lane = tid & 63;
    const int w = tid >> 6;              // 0..7
    const int wm = w >> 2, wn = w & 3;   // 2 x 4 wave grid
    const int colq = lane & 15, rowq = lane >> 4;

    // XCD-aware bijective swizzle: XCD k owns one fixed-N block row (B-panel L2-resident)
    const int orig = blockIdx.y * 64 + blockIdx.x;      // 512 blocks
    const int swz = (orig & 7) * 64 + (orig >> 3);
    const int m0 = (swz & 63) * 256;
    const int n0g = (swz >> 6) * 256;

    // staging: thread -> (row = tid>>2, slot = tid&3); source k-chunk XOR-swizzled
    const int srow = tid >> 2;                       // 0..127
    const int ksrc = (((tid & 3) ^ ((tid >> 3) & 3)) * 8);
    // frag reads: slot = rowq ^ ((colq>>1)&3), byte = row*64 + slot*16
    const int aslot = ((rowq ^ ((colq >> 1) & 3)) * 8);

    f32x4 acc[8][4] = {};

    auto stage = [&](int ts) {
        const int bi = ts & 3;
        const int k0 = (ts < 32 ? ts : 31) * 32;
        const unsigned short* sa = Xb + (size_t)(m0 + srow) * 1024 + k0 + ksrc;
        const unsigned short* sb = Wt + (size_t)(n0g + srow) * 1024 + k0 + ksrc;
        unsigned short* la = &As[bi][tid * 8];
        unsigned short* lb = &Bs[bi][tid * 8];
        GLDS(sa, la);
        GLDS(sa + 128 * 1024, la + 4096);
        GLDS(sb, lb);
        GLDS(sb + 128 * 1024, lb + 4096);
    };

    // prologue: tiles 0..2 in flight
    stage(0); stage(1); stage(2);

    for (int t = 0; t < 32; ++t) {
        stage(t + 3);                                     // 4 issues (dummy re-stage past end)
        asm volatile("s_waitcnt vmcnt(12)" ::: "memory"); // tile t landed; 3 tiles in flight
        __builtin_amdgcn_s_barrier();
        asm volatile("" ::: "memory");

        const int bi = t & 3;
        bf16x8 af[8], bfr[4];
#pragma unroll
        for (int f = 0; f < 8; ++f)
            af[f] = *(const bf16x8*)&As[bi][(wm * 128 + f * 16 + colq) * 32 + aslot];
#pragma unroll
        for (int f = 0; f < 4; ++f)
            bfr[f] = *(const bf16x8*)&Bs[bi][(wn * 64 + f * 16 + colq) * 32 + aslot];

        __builtin_amdgcn_s_setprio(1);
#pragma unroll
        for (int i2 = 0; i2 < 8; ++i2)
#pragma unroll
            for (int j2 = 0; j2 < 4; ++j2)
                acc[i2][j2] = __builtin_amdgcn_mfma_f32_16x16x32_bf16(af[i2], bfr[j2], acc[i2][j2], 0, 0, 0);
        __builtin_amdgcn_s_setprio(0);
        asm volatile("" ::: "memory");
        __builtin_amdgcn_s_barrier();
    }

    const bool isE = (n0g < 1024);
    const float* bias = isE ? eb : wb;
    const int nb = isE ? n0g : (n0g - 1024);
    unsigned short* outp = isE ? Ag : WXg;
#pragma unroll
    for (int j2 = 0; j2 < 4; ++j2) {
        const int gn = nb + wn * 64 + j2 * 16 + colq;
        const float bv = bias[gn];
#pragma unroll
        for (int i2 = 0; i2 < 8; ++i2) {
            const int gm = m0 + wm * 128 + i2 * 16 + rowq * 4;
#pragma unroll
            for (int r = 0; r < 4; ++r) {
                const size_t oidx = (size_t)(gm + r) * 1024 + gn;
                const float z = acc[i2][j2][r] + bv;
                float val;
                if (isE) val = 1.0f / (1.0f + __expf(z));                     // a = 1 - sigmoid(z)
                else     val = (1.0f / (1.0f + __expf(-z))) * xf[oidx];       // w * x
                outp[oidx] = f2bf(val);
            }
        }
    }
}

// ---------------- scan phase 1: per-chunk summaries (Lc=64), 2 chains/thread ----------------
__global__ __launch_bounds__(256) void scan_phase1(const unsigned short* __restrict__ Ag,
                                                   const unsigned short* __restrict__ WXg,
                                                   float* __restrict__ Asum, float* __restrict__ Bsum) {
    const int c = blockIdx.x, b = blockIdx.y, dz = blockIdx.z;
    const int d2 = dz * 256 + threadIdx.x;  // 0..511
    size_t base = ((size_t)(b * 4096 + c * 64)) * 512 + d2;
    const unsigned* A2 = (const unsigned*)Ag;
    const unsigned* W2 = (const unsigned*)WXg;
    float ap0 = 1.f, ap1 = 1.f, s0 = 0.f, s1 = 0.f;
#pragma unroll 8
    for (int i = 0; i < 64; ++i) {
        unsigned ua = A2[base], uw = W2[base];
        float a0 = bf2f(ua & 0xffffu), a1 = bf2f(ua >> 16);
        float w0 = bf2f(uw & 0xffffu), w1 = bf2f(uw >> 16);
        s0 = fmaf(s0, a0, w0);
        s1 = fmaf(s1, a1, w1);
        ap0 *= a0;
        ap1 *= a1;
        base += 512;
    }
    const size_t so = ((size_t)(b * 64 + c)) * 512 + d2;
    ((float2*)Asum)[so] = make_float2(ap0, ap1);
    ((float2*)Bsum)[so] = make_float2(s0, s1);
}

// ---------------- scan phase 2: combine chunk summaries -> chunk entry states ----------------
__global__ __launch_bounds__(256) void scan_phase2(const float* __restrict__ st,
                                                   const float* __restrict__ Asum,
                                                   const float* __restrict__ Bsum,
                                                   float* __restrict__ Sin) {
    const int t = blockIdx.x * 256 + threadIdx.x;  // 0..4095 = b*1024 + d
    const int b = t >> 10, d = t & 1023;
    float s = st[t];
    size_t idx = (size_t)(b * 64) * 1024 + d;
#pragma unroll 8
    for (int c = 0; c < 64; ++c) {
        Sin[idx] = s;
        s = fmaf(s, Asum[idx], Bsum[idx]);
        idx += 1024;
    }
}

// ---------------- scan phase 3: recompute with entry state, write out ----------------
__global__ __launch_bounds__(256) void scan_phase3(const unsigned short* __restrict__ Ag,
                                                   const unsigned short* __restrict__ WXg,
                                                   const float* __restrict__ Sin,
                                                   float* __restrict__ out) {
    const int c = blockIdx.x, b = blockIdx.y, dz = blockIdx.z;
    const int d2 = dz * 256 + threadIdx.x;
    size_t base = ((size_t)(b * 4096 + c * 64)) * 512 + d2;
    const unsigned* A2 = (const unsigned*)Ag;
    const unsigned* W2 = (const unsigned*)WXg;
    float2 sv = ((const float2*)Sin)[((size_t)(b * 64 + c)) * 512 + d2];
    float s0 = sv.x, s1 = sv.y;
    float2* o2 = (float2*)out;
#pragma unroll 4
    for (int i = 0; i < 64; ++i) {
        unsigned ua = A2[base], uw = W2[base];
        s0 = fmaf(s0, bf2f(ua & 0xffffu), bf2f(uw & 0xffffu));
        s1 = fmaf(s1, bf2f(ua >> 16), bf2f(uw >> 16));
        o2[base] = make_float2(s0, s1);
        base += 512;
    }
}

extern "C" void kernel_launch(void* const* d_in, const int* in_sizes, int n_in,
                              void* d_out, int out_size, void* d_ws, size_t ws_size,
                              hipStream_t stream) {
    const float* x  = (const float*)d_in[0];
    const float* st = (const float*)d_in[1];
    const float* ek = (const float*)d_in[2];
    const float* eb = (const float*)d_in[3];
    const float* wk = (const float*)d_in[4];
    const float* wb = (const float*)d_in[5];
    float* out = (float*)d_out;
    char* ws = (char*)d_ws;

    unsigned short* xb = (unsigned short*)ws;               // 32 MB bf16 x
    unsigned short* wt = (unsigned short*)(ws + 32 * MB);   // 4 MB bf16 Wt
    unsigned short* Ag = (unsigned short*)(ws + 36 * MB);   // 32 MB bf16 gates a
    unsigned short* WXg = (unsigned short*)(ws + 68 * MB);  // 32 MB bf16 w*x
    float* Asum = (float*)(ws + 100 * MB);                  // 1 MB
    float* Bsum = Asum + (size_t)4 * 64 * 1024;             // 1 MB
    float* Sin  = Bsum + (size_t)4 * 64 * 1024;             // 1 MB

    cvt_x_kernel<<<8192, 256, 0, stream>>>(x, xb, 2097152);
    cvt_w_kernel<<<1024, 256, 0, stream>>>(ek, wk, wt);

    dim3 ggrid(64, 8);
    gate_gemm<<<ggrid, 512, 0, stream>>>(xb, wt, eb, wb, x, Ag, WXg);

    dim3 sgrid(64, 4, 2);
    scan_phase1<<<sgrid, 256, 0, stream>>>(Ag, WXg, Asum, Bsum);
    scan_phase2<<<16, 256, 0, stream>>>(st, Asum, Bsum, Sin);
    scan_phase3<<<sgrid, 256, 0, stream>>>(Ag, WXg, Sin, out);
}

// Round 3
// 290.055 us; speedup vs baseline: 1.2115x; 1.2115x over previous
//
#include <hip/hip_runtime.h>
#include <stdint.h>

#define MB (1ull << 20)

typedef __attribute__((ext_vector_type(8))) short bf16x8;
typedef __attribute__((ext_vector_type(8))) unsigned short u16x8;
typedef __attribute__((ext_vector_type(4))) float f32x4;

static __device__ __forceinline__ unsigned short f2bf(float f) {
    unsigned u = __builtin_bit_cast(unsigned, f);
    u += 0x7fffu + ((u >> 16) & 1u);   // round-to-nearest-even
    return (unsigned short)(u >> 16);
}
static __device__ __forceinline__ float bf2f(unsigned u16) {
    return __builtin_bit_cast(float, u16 << 16);
}

#define GLDS(gp, lp) __builtin_amdgcn_global_load_lds(                                   \
        (const __attribute__((address_space(1))) void*)(gp),                             \
        (__attribute__((address_space(3))) void*)(lp), 16, 0, 0)

// raw s_barrier is NOT an IR memory fence; pin memory ops on both sides.
static __device__ __forceinline__ void wg_barrier() {
    asm volatile("" ::: "memory");
    __builtin_amdgcn_s_barrier();
    asm volatile("" ::: "memory");
}

// ---------------- prep: x f32 -> bf16 ----------------
__global__ __launch_bounds__(256) void cvt_x_kernel(const float* __restrict__ x,
                                                    unsigned short* __restrict__ xb, int n8) {
    int i = blockIdx.x * blockDim.x + threadIdx.x;
    if (i >= n8) return;
    const float4* px = (const float4*)x + (size_t)i * 2;
    float4 a = px[0], b = px[1];
    u16x8 o;
    o[0] = f2bf(a.x); o[1] = f2bf(a.y); o[2] = f2bf(a.z); o[3] = f2bf(a.w);
    o[4] = f2bf(b.x); o[5] = f2bf(b.y); o[6] = f2bf(b.z); o[7] = f2bf(b.w);
    ((u16x8*)xb)[i] = o;
}

// ---------------- prep: Wt[n][k] = concat(ek,wk)^T as bf16 ----------------
__global__ __launch_bounds__(256) void cvt_w_kernel(const float* __restrict__ ek,
                                                    const float* __restrict__ wk,
                                                    unsigned short* __restrict__ wt) {
    int t = blockIdx.x * blockDim.x + threadIdx.x;  // 0 .. 2048*128-1
    int n = t >> 7;
    int kb = (t & 127) * 8;
    const float* src = (n < 1024) ? ek : wk;
    int col = n & 1023;
    u16x8 o;
#pragma unroll
    for (int j = 0; j < 8; ++j) o[j] = f2bf(src[(size_t)(kb + j) * 1024 + col]);
    ((u16x8*)wt)[t] = o;
}

// ---------------- fused dual-gate GEMM: [16384,1024] x [1024,2048] ----------------
// 256x256 tile, BK=64, 8 waves (2M x 4N), 4 phases per K-step, counted vmcnt(8),
// T2 XOR swizzle via pre-swizzled global source, T5 setprio, T1 XCD swizzle.
__global__ __launch_bounds__(512, 2) void gate_gemm(const unsigned short* __restrict__ Xb,
                                                    const unsigned short* __restrict__ Wt,
                                                    const float* __restrict__ eb,
                                                    const float* __restrict__ wb,
                                                    unsigned short* __restrict__ Ag,
                                                    unsigned short* __restrict__ WXg) {
    // A: [dbuf][half][128][64] at 0 and 16384 (ushort units); B same at 32768.
    __shared__ alignas(16) unsigned short S[65536];  // 128 KB
    const int tid = threadIdx.x;
    const int lane = tid & 63, w = tid >> 6;
    const int wm = w >> 2, wn = w & 3;
    const int colq = lane & 15, rowq = lane >> 4;

    // T1: XCD k owns one fixed-N column; all XCDs walk M in lockstep (L3-sync A reads)
    const int orig = blockIdx.x;                       // 512 blocks
    const int swz = (orig & 7) * 64 + (orig >> 3);
    const int m0 = (swz & 63) * 256;
    const int n0g = (swz >> 6) * 256;

    // staging precompute: 8 loads/thread/K-step. l 0..3 = A, 4..7 = B.
    // dest is LINEAR (base + lane*16B); source k-chunk pre-swizzled: c = slot ^ (row&7)
    uint soff[8], ldso[8];
#pragma unroll
    for (int l = 0; l < 8; ++l) {
        const int o = (l & 3) * 512 + tid;     // 16B unit within the 32KB tile
        const int half = o >> 10;
        const int r = (o >> 3) & 127;
        const int slot = o & 7;
        const int c = slot ^ (r & 7);
        const int grow = ((l < 4) ? m0 : n0g) + half * 128 + r;
        soff[l] = (uint)grow * 1024u + (uint)c * 8u;
        ldso[l] = (uint)((l < 4 ? 0 : 32768) + half * 8192 + r * 64 + slot * 8);
    }

    auto stage = [&](int s) {
        const int k0 = (s < 16 ? s : 15) * 64;
        const int db = (s & 1) * 16384;
#pragma unroll
        for (int l = 0; l < 8; ++l) {
            const unsigned short* g = ((l < 4) ? Xb : Wt) + soff[l] + k0;
            GLDS(g, &S[db + ldso[l]]);
        }
    };

    // fragment read offsets (swizzled): slotx(ks) = ((ks*4+rowq) ^ (colq&7)) * 8
    const int axk = colq & 7;
    const int abase = wm * 8192 + colq * 64;                         // + i2*1024
    const int bbase = 32768 + (wn >> 1) * 8192 + ((wn & 1) * 64 + colq) * 64;  // + j2*1024

    f32x4 acc[8][4] = {};
    bf16x8 af[4][2], bfr[2][2];

    stage(0);

    for (int s = 0; s < 16; ++s) {
        const int db = (s & 1) * 16384;
        // ---- phase 0: stage s+1, confirm s landed, MFMA Mq0 x Nq0 ----
        stage(s + 1);
        asm volatile("s_waitcnt vmcnt(8)" ::: "memory");  // step s fully in LDS (8 newest = s+1)
        wg_barrier();
#pragma unroll
        for (int i = 0; i < 4; ++i)
#pragma unroll
            for (int ks = 0; ks < 2; ++ks)
                af[i][ks] = *(const bf16x8*)&S[db + abase + i * 1024 + (((ks * 4 + rowq) ^ axk) * 8)];
#pragma unroll
        for (int j = 0; j < 2; ++j)
#pragma unroll
            for (int ks = 0; ks < 2; ++ks)
                bfr[j][ks] = *(const bf16x8*)&S[db + bbase + j * 1024 + (((ks * 4 + rowq) ^ axk) * 8)];
        __builtin_amdgcn_s_setprio(1);
#pragma unroll
        for (int i = 0; i < 4; ++i)
#pragma unroll
            for (int j = 0; j < 2; ++j)
#pragma unroll
                for (int ks = 0; ks < 2; ++ks)
                    acc[i][j] = __builtin_amdgcn_mfma_f32_16x16x32_bf16(af[i][ks], bfr[j][ks], acc[i][j], 0, 0, 0);
        __builtin_amdgcn_s_setprio(0);
        wg_barrier();

        // ---- phase 1: read B Nq1, MFMA Mq0 x Nq1 ----
#pragma unroll
        for (int j = 0; j < 2; ++j)
#pragma unroll
            for (int ks = 0; ks < 2; ++ks)
                bfr[j][ks] = *(const bf16x8*)&S[db + bbase + (2 + j) * 1024 + (((ks * 4 + rowq) ^ axk) * 8)];
        wg_barrier();
        __builtin_amdgcn_s_setprio(1);
#pragma unroll
        for (int i = 0; i < 4; ++i)
#pragma unroll
            for (int j = 0; j < 2; ++j)
#pragma unroll
                for (int ks = 0; ks < 2; ++ks)
                    acc[i][2 + j] = __builtin_amdgcn_mfma_f32_16x16x32_bf16(af[i][ks], bfr[j][ks], acc[i][2 + j], 0, 0, 0);
        __builtin_amdgcn_s_setprio(0);
        wg_barrier();

        // ---- phase 2: read A Mq1, MFMA Mq1 x Nq1 ----
#pragma unroll
        for (int i = 0; i < 4; ++i)
#pragma unroll
            for (int ks = 0; ks < 2; ++ks)
                af[i][ks] = *(const bf16x8*)&S[db + abase + (4 + i) * 1024 + (((ks * 4 + rowq) ^ axk) * 8)];
        wg_barrier();
        __builtin_amdgcn_s_setprio(1);
#pragma unroll
        for (int i = 0; i < 4; ++i)
#pragma unroll
            for (int j = 0; j < 2; ++j)
#pragma unroll
                for (int ks = 0; ks < 2; ++ks)
                    acc[4 + i][2 + j] = __builtin_amdgcn_mfma_f32_16x16x32_bf16(af[i][ks], bfr[j][ks], acc[4 + i][2 + j], 0, 0, 0);
        __builtin_amdgcn_s_setprio(0);
        wg_barrier();

        // ---- phase 3: re-read B Nq0, MFMA Mq1 x Nq0 ----
#pragma unroll
        for (int j = 0; j < 2; ++j)
#pragma unroll
            for (int ks = 0; ks < 2; ++ks)
                bfr[j][ks] = *(const bf16x8*)&S[db + bbase + j * 1024 + (((ks * 4 + rowq) ^ axk) * 8)];
        wg_barrier();
        __builtin_amdgcn_s_setprio(1);
#pragma unroll
        for (int i = 0; i < 4; ++i)
#pragma unroll
            for (int j = 0; j < 2; ++j)
#pragma unroll
                for (int ks = 0; ks < 2; ++ks)
                    acc[4 + i][j] = __builtin_amdgcn_mfma_f32_16x16x32_bf16(af[i][ks], bfr[j][ks], acc[4 + i][j], 0, 0, 0);
        __builtin_amdgcn_s_setprio(0);
        wg_barrier();
    }

    // ---- epilogue: sigmoid -> per-wave LDS (f32, XOR-swizzled) -> 16B bf16 stores ----
    const bool isE = (n0g < 1024);
    const float* bias = isE ? eb : wb;
    const int nb = isE ? n0g : (n0g - 1024);
    unsigned short* outp = isE ? Ag : WXg;
    float bv[4];
#pragma unroll
    for (int j = 0; j < 4; ++j) bv[j] = bias[nb + wn * 64 + j * 16 + colq];

    float* Ep = (float*)S;             // per-wave region: 4096 floats (16 KB)
    const int wbase = w * 4096;
    const int rl = lane >> 3;          // 0..7
    const int c0 = (lane & 7) * 8;

#pragma unroll
    for (int ih = 0; ih < 2; ++ih) {
        __syncthreads();
#pragma unroll
        for (int i = 0; i < 4; ++i)
#pragma unroll
            for (int j = 0; j < 4; ++j)
#pragma unroll
                for (int r = 0; r < 4; ++r) {
                    const int r2 = i * 16 + rowq * 4 + r;
                    const int cc = (j * 16 + colq) ^ (rowq * 16);
                    const float z = acc[ih * 4 + i][j][r] + bv[j];
                    Ep[wbase + r2 * 64 + cc] = 1.0f / (1.0f + __expf(isE ? z : -z));
                }
        __syncthreads();
#pragma unroll
        for (int it = 0; it < 8; ++it) {
            const int rr = it * 8 + rl;
            const int key = ((rr >> 2) & 3) * 16;
            const int cx = c0 ^ key;
            f32x4 v0 = *(const f32x4*)&Ep[wbase + rr * 64 + cx];
            f32x4 v1 = *(const f32x4*)&Ep[wbase + rr * 64 + cx + 4];
            const int grow = m0 + wm * 128 + ih * 64 + rr;
            const size_t oidx = (size_t)grow * 1024 + (nb + wn * 64 + c0);
            u16x8 ov;
            if (isE) {
                ov[0] = f2bf(v0[0]); ov[1] = f2bf(v0[1]); ov[2] = f2bf(v0[2]); ov[3] = f2bf(v0[3]);
                ov[4] = f2bf(v1[0]); ov[5] = f2bf(v1[1]); ov[6] = f2bf(v1[2]); ov[7] = f2bf(v1[3]);
            } else {
                u16x8 xv = *(const u16x8*)&Xb[oidx];
#pragma unroll
                for (int q = 0; q < 4; ++q) {
                    ov[q]     = f2bf(v0[q] * bf2f((unsigned)(unsigned short)xv[q]));
                    ov[4 + q] = f2bf(v1[q] * bf2f((unsigned)(unsigned short)xv[4 + q]));
                }
            }
            *(u16x8*)&outp[oidx] = ov;
        }
    }
}

// ---------------- scan phase 1: per-chunk summaries (Lc=64), 4 chains/thread ----------------
__global__ __launch_bounds__(256) void scan_phase1(const unsigned short* __restrict__ Ag,
                                                   const unsigned short* __restrict__ WXg,
                                                   float* __restrict__ Asum, float* __restrict__ Bsum) {
    const int c = blockIdx.x, b = blockIdx.y;
    const int d4 = threadIdx.x;  // 0..255, covers d = d4*4 .. +3
    size_t base = ((size_t)(b * 4096 + c * 64)) * 256 + d4;
    const uint2* A2 = (const uint2*)Ag;
    const uint2* W2 = (const uint2*)WXg;
    float ap[4] = {1.f, 1.f, 1.f, 1.f}, sv[4] = {0.f, 0.f, 0.f, 0.f};
#pragma unroll 8
    for (int i = 0; i < 64; ++i) {
        uint2 ua = A2[base], uw = W2[base];
        float a0 = bf2f(ua.x & 0xffffu), a1 = bf2f(ua.x >> 16);
        float a2 = bf2f(ua.y & 0xffffu), a3 = bf2f(ua.y >> 16);
        float w0 = bf2f(uw.x & 0xffffu), w1 = bf2f(uw.x >> 16);
        float w2 = bf2f(uw.y & 0xffffu), w3 = bf2f(uw.y >> 16);
        sv[0] = fmaf(sv[0], a0, w0); sv[1] = fmaf(sv[1], a1, w1);
        sv[2] = fmaf(sv[2], a2, w2); sv[3] = fmaf(sv[3], a3, w3);
        ap[0] *= a0; ap[1] *= a1; ap[2] *= a2; ap[3] *= a3;
        base += 256;
    }
    const size_t so = ((size_t)(b * 64 + c)) * 256 + d4;
    ((float4*)Asum)[so] = make_float4(ap[0], ap[1], ap[2], ap[3]);
    ((float4*)Bsum)[so] = make_float4(sv[0], sv[1], sv[2], sv[3]);
}

// ---------------- scan phase 2: combine chunk summaries -> chunk entry states ----------------
__global__ __launch_bounds__(256) void scan_phase2(const float* __restrict__ st,
                                                   const float* __restrict__ Asum,
                                                   const float* __restrict__ Bsum,
                                                   float* __restrict__ Sin) {
    const int t = blockIdx.x * 256 + threadIdx.x;  // 0..4095 = b*1024 + d
    const int b = t >> 10, d = t & 1023;
    float s = st[t];
    size_t idx = (size_t)(b * 64) * 1024 + d;
#pragma unroll 8
    for (int c = 0; c < 64; ++c) {
        Sin[idx] = s;
        s = fmaf(s, Asum[idx], Bsum[idx]);
        idx += 1024;
    }
}

// ---------------- scan phase 3: recompute with entry state, write out ----------------
__global__ __launch_bounds__(256) void scan_phase3(const unsigned short* __restrict__ Ag,
                                                   const unsigned short* __restrict__ WXg,
                                                   const float* __restrict__ Sin,
                                                   float* __restrict__ out) {
    const int c = blockIdx.x, b = blockIdx.y;
    const int d4 = threadIdx.x;
    size_t base = ((size_t)(b * 4096 + c * 64)) * 256 + d4;
    const uint2* A2 = (const uint2*)Ag;
    const uint2* W2 = (const uint2*)WXg;
    float4 svv = ((const float4*)Sin)[((size_t)(b * 64 + c)) * 256 + d4];
    float s0 = svv.x, s1 = svv.y, s2 = svv.z, s3 = svv.w;
    float4* o4 = (float4*)out;
#pragma unroll 4
    for (int i = 0; i < 64; ++i) {
        uint2 ua = A2[base], uw = W2[base];
        s0 = fmaf(s0, bf2f(ua.x & 0xffffu), bf2f(uw.x & 0xffffu));
        s1 = fmaf(s1, bf2f(ua.x >> 16),     bf2f(uw.x >> 16));
        s2 = fmaf(s2, bf2f(ua.y & 0xffffu), bf2f(uw.y & 0xffffu));
        s3 = fmaf(s3, bf2f(ua.y >> 16),     bf2f(uw.y >> 16));
        o4[base] = make_float4(s0, s1, s2, s3);
        base += 256;
    }
}

extern "C" void kernel_launch(void* const* d_in, const int* in_sizes, int n_in,
                              void* d_out, int out_size, void* d_ws, size_t ws_size,
                              hipStream_t stream) {
    const float* x  = (const float*)d_in[0];
    const float* st = (const float*)d_in[1];
    const float* ek = (const float*)d_in[2];
    const float* eb = (const float*)d_in[3];
    const float* wk = (const float*)d_in[4];
    const float* wb = (const float*)d_in[5];
    float* out = (float*)d_out;
    char* ws = (char*)d_ws;

    unsigned short* xb = (unsigned short*)ws;               // 32 MB bf16 x
    unsigned short* wt = (unsigned short*)(ws + 32 * MB);   // 4 MB bf16 Wt
    unsigned short* Ag = (unsigned short*)(ws + 36 * MB);   // 32 MB bf16 gates a
    unsigned short* WXg = (unsigned short*)(ws + 68 * MB);  // 32 MB bf16 w*x
    float* Asum = (float*)(ws + 100 * MB);                  // 1 MB
    float* Bsum = Asum + (size_t)4 * 64 * 1024;             // 1 MB
    float* Sin  = Bsum + (size_t)4 * 64 * 1024;             // 1 MB

    cvt_x_kernel<<<8192, 256, 0, stream>>>(x, xb, 2097152);
    cvt_w_kernel<<<1024, 256, 0, stream>>>(ek, wk, wt);

    gate_gemm<<<512, 512, 0, stream>>>(xb, wt, eb, wb, Ag, WXg);

    dim3 sgrid(64, 4);
    scan_phase1<<<sgrid, 256, 0, stream>>>(Ag, WXg, Asum, Bsum);
    scan_phase2<<<16, 256, 0, stream>>>(st, Asum, Bsum, Sin);
    scan_phase3<<<sgrid, 256, 0, stream>>>(Ag, WXg, Sin, out);
}